// Round 10
// baseline (4324.687 us; speedup 1.0000x reference)
//
#include <hip/hip_runtime.h>
#include <stdint.h>

// 3-layer LSTM (H=64, B=256, S=4096, DIN=1) + linear head.
// R15: ONE WAVE PER LAYER. 256 blocks x 256 thr = 4 waves (l0,l1,l2,head),
// 1 wave/SIMD (waves_per_eu(1,1), ~380 VGPR). Each layer wave does the whole
// layer step: 16 N-tiles x KT K-tiles = 32/64 MFMAs (per-CU MFMA count
// unchanged vs R12c's 162/tick -- the 4-wave split never reduced it).
// Why: R14 showed flag-sync overhead = 12 ds_reads/step + in-group
// round-trips; R12c showed the barrier serializes MFMA and VALU bursts
// chip-wide (tick = MfmaUtil + VALUBusy exactly). With one wave per layer:
//  - in-group sync GONE (wave is self-synchronized);
//  - self-recurrence is wave-local: ds_write h, lgkm, ds_read A-frags;
//  - inter-layer sync = 1 flag/layer, 1 ds_read/poll; anti-overwrite
//    (ring depth 4) checked only every 4th step;
//  - lane l owns unit l exactly (q-select via 12 cndmask); 25 VALU act;
//  - 4 free-running waves on 4 SIMDs drift -> MFMA bursts interleave on the
//    CU matrix pipe (m114) instead of phase-locking behind a barrier.
// Carried: h=A-operand row-replicated MFMA; pre-packed pinned B-frags
// (prep kernel UNCHANGED: tile t == old w*4+j); bounded spins (no hangs);
// y staged 32/store on the head wave.

#define SQ 4096
#define HH 64
#define NB 256
#define SPIN 32768

typedef _Float16 h2    __attribute__((ext_vector_type(2)));
typedef _Float16 f16x8 __attribute__((ext_vector_type(8)));
typedef float    f32x4 __attribute__((ext_vector_type(4)));

__device__ __forceinline__ float frcp(float x)  { return __builtin_amdgcn_rcpf(x); }
__device__ __forceinline__ float fexp2(float x) { return __builtin_amdgcn_exp2f(x); }

__device__ __forceinline__ void pin4(uint4& r) {
    asm volatile("" : "+v"(r.x), "+v"(r.y), "+v"(r.z), "+v"(r.w));
}
__device__ __forceinline__ void pinv(f32x4& r) {
    float t0 = r[0], t1 = r[1], t2 = r[2], t3 = r[3];
    asm volatile("" : "+v"(t0), "+v"(t1), "+v"(t2), "+v"(t3));
    r[0] = t0; r[1] = t1; r[2] = t2; r[3] = t3;
}

__device__ __forceinline__ int fldi(const int* p) {
    return __hip_atomic_load(p, __ATOMIC_RELAXED, __HIP_MEMORY_SCOPE_WORKGROUP);
}
__device__ __forceinline__ void fsti(int* p, int v) {
    __hip_atomic_store(p, v, __ATOMIC_RELAXED, __HIP_MEMORY_SCOPE_WORKGROUP);
}

// D = A(h, rows replicated) x B(weights) + C
__device__ __forceinline__ f32x4 mm(uint4 hv, uint4 wv, f32x4 c) {
    return __builtin_amdgcn_mfma_f32_16x16x32_f16(
        __builtin_bit_cast(f16x8, hv), __builtin_bit_cast(f16x8, wv), c, 0, 0, 0);
}

// ---- prep: fp32 weights -> MFMA B-fragments (packed fp16 pairs). UNCHANGED.
// Regions: l0 [0,8192) u32 (Whh0, KT=2); l1 [8192,24576) ([Wih1|Whh1], KT=4);
// l2 [24576,40960) ([Wih2|Whh2], KT=4); y-frag [40960,41472).
// Tile t = ub*4 + g (ub = unit-block, g = gate): frag (t,kt) at
// gbase + ((t*KT + kt)*64 + lane)*4 + jj; row = 64g + 16ub + n.
__global__ __launch_bounds__(256)
void prep_weights(const float* __restrict__ Whh0, const float* __restrict__ Wih1,
                  const float* __restrict__ Whh1, const float* __restrict__ Wih2,
                  const float* __restrict__ Whh2, const float* __restrict__ Wlin,
                  uint32_t* __restrict__ ws)
{
    const int idx = blockIdx.x * 256 + threadIdx.x;   // 0..41471
    if (idx >= 40960) {                               // y-fragment region
        const int r  = idx - 40960;
        const int jj = r & 3;
        const int l  = (r >> 2) & 63;
        const int kk = (r >> 8) & 1;
        const int n  = l & 15;
        const int krow = ((l >> 4) << 3) + 2 * jj;
        const int ku   = 32 * kk + krow;
        h2 t;
        t[0] = (_Float16)((n == 0) ? Wlin[ku]     : 0.f);
        t[1] = (_Float16)((n == 0) ? Wlin[ku + 1] : 0.f);
        ws[idx] = __builtin_bit_cast(uint32_t, t);
        return;
    }
    int r, ktbits;
    const float *Wi = nullptr, *Wh;
    if (idx < 8192)       { r = idx;         ktbits = 1; Wh = Whh0; }
    else if (idx < 24576) { r = idx - 8192;  ktbits = 2; Wi = Wih1; Wh = Whh1; }
    else                  { r = idx - 24576; ktbits = 2; Wi = Wih2; Wh = Whh2; }
    const int jj  = r & 3;
    const int l   = (r >> 2) & 63;
    const int rem = r >> 8;
    const int kt  = rem & ((1 << ktbits) - 1);
    const int tw  = rem >> ktbits;
    const int j   = tw & 3;            // gate g
    const int w   = tw >> 2;           // unit-block ub
    const int n   = l & 15;
    const int krow = ((l >> 4) << 3) + 2 * jj;
    const int orow = 64 * j + 16 * w + n;
    int kcol = 32 * kt + krow;
    const float* M;
    if (ktbits == 1)    { M = Wh; }
    else if (kcol < 64) { M = Wi; }
    else                { M = Wh; kcol -= 64; }
    h2 t;
    t[0] = (_Float16)M[orow * HH + kcol];
    t[1] = (_Float16)M[orow * HH + kcol + 1];
    ws[idx] = __builtin_bit_cast(uint32_t, t);
}

// ---- per-layer wave body. Lane l owns unit l (u = 16*(l>>4) + (l&15) = l).
template<int GRP>
__device__ __forceinline__ void run_layer(
    int b, int l,
    const uint32_t* __restrict__ wpk,
    const float* __restrict__ Wih0,
    const float* __restrict__ bi, const float* __restrict__ bh,
    float* __restrict__ out,
    const float* xrow, _Float16 (*hb)[3][64], int* pf)
{
    constexpr int KT = (GRP == 0) ? 2 : 4;
    constexpr int GB = (GRP == 0) ? 0 : (GRP == 1) ? 8192 : 24576;
    const int q  = l >> 4;
    const bool qb0 = (q & 1) != 0, qb1 = (q & 2) != 0;

    uint4 wf[16][KT];
#pragma unroll
    for (int t = 0; t < 16; ++t)
#pragma unroll
        for (int kt = 0; kt < KT; ++kt) {
            wf[t][kt] = *reinterpret_cast<const uint4*>(
                wpk + GB + ((t * KT + kt) * 64 + l) * 4);
            pin4(wf[t][kt]);
        }

    float bs[4], wx[4] = {0.f, 0.f, 0.f, 0.f};
#pragma unroll
    for (int g = 0; g < 4; ++g) bs[g] = bi[64 * g + l] + bh[64 * g + l];
    if (GRP == 0)
#pragma unroll
        for (int g = 0; g < 4; ++g) wx[g] = Wih0[64 * g + l];

    const f32x4 Z = {0.f, 0.f, 0.f, 0.f};
    float cc = 0.f;

    for (int s = 0; s < SQ; ++s) {
        // poll: producer h(s) ready (every step); consumer past slot s-4
        // (ring depth 4 -> only needs checking every 4th step, bound s).
        const bool need_cons = ((s & 3) == 0);
        for (int it = 0; it < SPIN; ++it) {
            bool ok = true;
            if (GRP != 0)  ok = fldi(&pf[GRP - 1]) >= s + 1;
            if (need_cons) ok = ok && (fldi(&pf[GRP + 1]) >= s);
            if (ok) break;
        }

        const int sa = s & 3, so = (s + 3) & 3;
        uint4 a[KT];
        if (GRP == 0) {
            const _Float16* ho_ = &hb[so][0][0];        // own h(s-1)
            a[0] = *(const uint4*)(ho_ + q * 8);
            a[1] = *(const uint4*)(ho_ + 32 + q * 8);
        } else {
            const _Float16* hi_ = &hb[sa][GRP - 1][0];  // input h(s)
            const _Float16* ho_ = &hb[so][GRP][0];      // own h(s-1)
            a[0] = *(const uint4*)(hi_ + q * 8);
            a[1] = *(const uint4*)(hi_ + 32 + q * 8);
            a[2] = *(const uint4*)(ho_ + q * 8);
            a[3] = *(const uint4*)(ho_ + 32 + q * 8);
        }

        f32x4 acc[16];
#pragma unroll
        for (int t = 0; t < 16; ++t) acc[t] = mm(a[0], wf[t][0], Z);
#pragma unroll
        for (int kt = 1; kt < KT; ++kt)
#pragma unroll
            for (int t = 0; t < 16; ++t) acc[t] = mm(a[kt], wf[t][kt], acc[t]);

        // q-select: tile t = q*4+g holds gate g of this lane's unit
        float g4[4];
#pragma unroll
        for (int g = 0; g < 4; ++g) {
            const float lo = qb0 ? acc[4 + g][0]  : acc[g][0];
            const float hi = qb0 ? acc[12 + g][0] : acc[8 + g][0];
            g4[g] = (qb1 ? hi : lo) + bs[g];
        }
        if (GRP == 0) {
            const float xT = xrow[s];
#pragma unroll
            for (int g = 0; g < 4; ++g) g4[g] += wx[g] * xT;
        }

        const float i_ = frcp(1.f + fexp2(g4[0] * -1.44269504f));
        const float f_ = frcp(1.f + fexp2(g4[1] * -1.44269504f));
        const float tg = 2.f * frcp(1.f + fexp2(g4[2] * -2.88539008f)) - 1.f;
        const float o_ = frcp(1.f + fexp2(g4[3] * -1.44269504f));
        cc = f_ * cc + i_ * tg;
        const float tc = fminf(fmaxf(cc, -15.f), 15.f);
        const float e  = fexp2(tc * -2.88539008f);
        const float h  = o_ * ((1.f - e) * frcp(1.f + e));

        hb[sa][GRP][l] = (_Float16)h;                   // lane l -> unit l
        if (s == SQ - 1) {
            out[NB * SQ + GRP * NB * HH + b * HH + l] = h;
            out[NB * SQ + 3 * NB * HH + GRP * NB * HH + b * HH + l] = cc;
        }
        // publish: h-write drained before flag store
        asm volatile("s_waitcnt lgkmcnt(0)" ::: "memory");
        __builtin_amdgcn_sched_barrier(0);
        if (l == 0) fsti(&pf[GRP], s + 1);
    }
}

__global__ __launch_bounds__(256)
__attribute__((amdgpu_waves_per_eu(1, 1)))
void lstm3_fused(
    const float* __restrict__ x,
    const float* __restrict__ Wih0,
    const float* __restrict__ bih0, const float* __restrict__ bhh0,
    const float* __restrict__ bih1, const float* __restrict__ bhh1,
    const float* __restrict__ bih2, const float* __restrict__ bhh2,
    const float* __restrict__ blin,
    const uint32_t* __restrict__ wpk,
    float* __restrict__ out)
{
    const int b   = blockIdx.x;
    const int tid = threadIdx.x;
    const int wid = tid >> 6;          // 0,1,2 = layers; 3 = head
    const int l   = tid & 63;

    __shared__ __align__(16) float xrow[SQ];
    __shared__ __align__(16) _Float16 hb[4][3][64];   // [slot][layer][unit]
    __shared__ __align__(16) float ystage[32];
    __shared__ __align__(16) int pf[4];   // steps completed per wave role

    for (int i = tid; i < SQ; i += 256) xrow[i] = x[b * SQ + i];
    if (tid < 96) ((uint4*)hb)[tid] = make_uint4(0, 0, 0, 0);
    if (tid < 4) pf[tid] = 0;
    __syncthreads();

    if (wid == 3) {
        // ---- head wave: y(s) = Wlin . h2(s) + blin ----
        const int q = l >> 4;
        uint4 wy0 = *reinterpret_cast<const uint4*>(wpk + 40960 + l * 4);
        uint4 wy1 = *reinterpret_cast<const uint4*>(wpk + 40960 + (64 + l) * 4);
        pin4(wy0); pin4(wy1);
        const float bv = blin[0];
        f32x4 cy = {bv, bv, bv, bv};
        pinv(cy);
        for (int s = 0; s < SQ; ++s) {
            for (int it = 0; it < SPIN; ++it) {
                if (fldi(&pf[2]) >= s + 1) break;
            }
            const _Float16* h2p = &hb[s & 3][2][0];
            const uint4 a0 = *(const uint4*)(h2p + q * 8);
            const uint4 a1 = *(const uint4*)(h2p + 32 + q * 8);
            f32x4 d = mm(a0, wy0, cy);
            d = mm(a1, wy1, d);
            if (l == 0) ystage[s & 31] = d[0];
            asm volatile("s_waitcnt lgkmcnt(0)" ::: "memory");
            __builtin_amdgcn_sched_barrier(0);
            if (l == 0) fsti(&pf[3], s + 1);
            if ((s & 31) == 31) {
                const float yv = ystage[l & 31];
                if (l < 32) out[b * SQ + (s - 31) + l] = yv;
            }
        }
        return;
    }

    if (wid == 0)
        run_layer<0>(b, l, wpk, Wih0, bih0, bhh0, out, xrow, hb, pf);
    else if (wid == 1)
        run_layer<1>(b, l, wpk, Wih0, bih1, bhh1, out, xrow, hb, pf);
    else
        run_layer<2>(b, l, wpk, Wih0, bih2, bhh2, out, xrow, hb, pf);
}

extern "C" void kernel_launch(void* const* d_in, const int* in_sizes, int n_in,
                              void* d_out, int out_size, void* d_ws, size_t ws_size,
                              hipStream_t stream) {
    const float* x    = (const float*)d_in[0];
    const float* Wih0 = (const float*)d_in[1];
    const float* Whh0 = (const float*)d_in[2];
    const float* bih0 = (const float*)d_in[3];
    const float* bhh0 = (const float*)d_in[4];
    const float* Wih1 = (const float*)d_in[5];
    const float* Whh1 = (const float*)d_in[6];
    const float* bih1 = (const float*)d_in[7];
    const float* bhh1 = (const float*)d_in[8];
    const float* Wih2 = (const float*)d_in[9];
    const float* Whh2 = (const float*)d_in[10];
    const float* bih2 = (const float*)d_in[11];
    const float* bhh2 = (const float*)d_in[12];
    const float* Wlin = (const float*)d_in[13];
    const float* blin = (const float*)d_in[14];
    float* out = (float*)d_out;

    uint32_t* wpk = (uint32_t*)d_ws;   // 41472 u32 = 162 KiB < ws_size
    prep_weights<<<162, 256, 0, stream>>>(Whh0, Wih1, Whh1, Wih2, Whh2, Wlin, wpk);
    lstm3_fused<<<NB, 256, 0, stream>>>(x, Wih0, bih0, bhh0,
                                        bih1, bhh1, bih2, bhh2,
                                        blin, wpk, out);
}

// Round 11
// 2625.908 us; speedup vs baseline: 1.6469x; 1.6469x over previous
//
#include <hip/hip_runtime.h>
#include <stdint.h>

// 3-layer LSTM (H=64, B=256, S=4096, DIN=1) + linear head.
// One block/batch element; 768 thr = 12 waves = 3 groups x 4 (group=layer).
// R16: intra-wave MFMA/VALU de-phasing via input-side prefetch.
// HW model (R12c+R15 counters): one 16x16x32 MFMA = ~19.4 cyc of SIMD matrix
// pipe; R12c = 40 MFMA/SIMD/tick = 776 cyc + 812 VALU = 1588 ~= tick 1510 ->
// pipes FULLY SERIALIZED (lockstep MFMA-then-act in every wave). R15 showed
// concentrating MFMA (64/wave on 1 SIMD = 1242 cyc) is worse -> keep the
// balanced 12-wave layout and de-phase INSIDE each wave:
//  - skew deepened to 2 ticks/layer (l0@T: step T, l1: T-2, l2: T-4,
//    head: T-5) -> h_in(s+1) is published BEFORE tick T starts;
//  - grp1/2 split the acc: carry acc_in(s) (input side, kt0-1) across ticks;
//    per tick: 8 self-MFMAs finish step s, then 8 PREFETCH MFMAs start
//    step s+1's input side (independent regs), then act(s) on the VALU
//    runs concurrently with the prefetch MFMAs still in the matrix pipe;
//  - all LDS reads remain age-1 -> R12c's 2-buffer ring unchanged;
//  - waves_per_eu(3) pins VGPR<=170 so the 12-wave block stays schedulable.
// Carried: h=A-operand row-replicated MFMA; pinned pre-packed B-frags;
// bias in persistent C regs; head 2 MFMAs on l0w1; y staged 32/store.

#define SQ 4096
#define HH 64
#define NB 256

typedef _Float16 h2    __attribute__((ext_vector_type(2)));
typedef _Float16 f16x8 __attribute__((ext_vector_type(8)));
typedef float    f32x4 __attribute__((ext_vector_type(4)));

__device__ __forceinline__ float frcp(float x)  { return __builtin_amdgcn_rcpf(x); }
__device__ __forceinline__ float fexp2(float x) { return __builtin_amdgcn_exp2f(x); }

__device__ __forceinline__ void pin4(uint4& r) {
    asm volatile("" : "+v"(r.x), "+v"(r.y), "+v"(r.z), "+v"(r.w));
}
__device__ __forceinline__ void pinv(f32x4& r) {
    float t0 = r[0], t1 = r[1], t2 = r[2], t3 = r[3];
    asm volatile("" : "+v"(t0), "+v"(t1), "+v"(t2), "+v"(t3));
    r[0] = t0; r[1] = t1; r[2] = t2; r[3] = t3;
}

// D = A(h, rows replicated) x B(weights) + C
__device__ __forceinline__ f32x4 mm(uint4 hv, uint4 wv, f32x4 c) {
    return __builtin_amdgcn_mfma_f32_16x16x32_f16(
        __builtin_bit_cast(f16x8, hv), __builtin_bit_cast(f16x8, wv), c, 0, 0, 0);
}

// ---- prep: fp32 weights -> MFMA B-fragments (packed fp16 pairs). UNCHANGED.
// Regions: grp0 [0,8192) u32 (Whh0, KT=2); grp1 [8192,24576) ([Wih1|Whh1],
// KT=4); grp2 [24576,40960) ([Wih2|Whh2], KT=4); y-frag [40960,41472).
__global__ __launch_bounds__(256)
void prep_weights(const float* __restrict__ Whh0, const float* __restrict__ Wih1,
                  const float* __restrict__ Whh1, const float* __restrict__ Wih2,
                  const float* __restrict__ Whh2, const float* __restrict__ Wlin,
                  uint32_t* __restrict__ ws)
{
    const int idx = blockIdx.x * 256 + threadIdx.x;   // 0..41471
    if (idx >= 40960) {                               // y-fragment region
        const int r  = idx - 40960;
        const int jj = r & 3;
        const int l  = (r >> 2) & 63;
        const int kk = (r >> 8) & 1;                  // 0 -> kt2, 1 -> kt3
        const int n  = l & 15;
        const int krow = ((l >> 4) << 3) + 2 * jj;
        const int ku   = 32 * kk + krow;              // h2 unit index
        h2 t;
        t[0] = (_Float16)((n == 0) ? Wlin[ku]     : 0.f);
        t[1] = (_Float16)((n == 0) ? Wlin[ku + 1] : 0.f);
        ws[idx] = __builtin_bit_cast(uint32_t, t);
        return;
    }
    int r, ktbits;
    const float *Wi = nullptr, *Wh;
    if (idx < 8192)       { r = idx;         ktbits = 1; Wh = Whh0; }
    else if (idx < 24576) { r = idx - 8192;  ktbits = 2; Wi = Wih1; Wh = Whh1; }
    else                  { r = idx - 24576; ktbits = 2; Wi = Wih2; Wh = Whh2; }
    const int jj  = r & 3;
    const int l   = (r >> 2) & 63;
    const int rem = r >> 8;
    const int kt  = rem & ((1 << ktbits) - 1);
    const int tw  = rem >> ktbits;
    const int j   = tw & 3;
    const int w   = tw >> 2;
    const int n   = l & 15;
    const int krow = ((l >> 4) << 3) + 2 * jj;
    const int orow = 64 * j + 16 * w + n;
    int kcol = 32 * kt + krow;
    const float* M;
    if (ktbits == 1)    { M = Wh; }
    else if (kcol < 64) { M = Wi; }
    else                { M = Wh; kcol -= 64; }
    h2 t;
    t[0] = (_Float16)M[orow * HH + kcol];
    t[1] = (_Float16)M[orow * HH + kcol + 1];
    ws[idx] = __builtin_bit_cast(uint32_t, t);
}

__global__ __launch_bounds__(768)
__attribute__((amdgpu_waves_per_eu(3)))
void lstm3_fused(
    const float* __restrict__ x,
    const float* __restrict__ Wih0,
    const float* __restrict__ bih0, const float* __restrict__ bhh0,
    const float* __restrict__ bih1, const float* __restrict__ bhh1,
    const float* __restrict__ bih2, const float* __restrict__ bhh2,
    const float* __restrict__ blin,
    const uint32_t* __restrict__ wpk,
    float* __restrict__ out)
{
    const int b    = blockIdx.x;
    const int tid  = threadIdx.x;
    const int grp  = tid >> 8;         // layer 0,1,2
    const int k    = tid & 255;
    const int w    = k >> 6;           // wave within group
    const int l    = k & 63;           // lane
    const int n    = l & 15;
    const int q    = l >> 4;           // 16-lane sub-group (A k-slice)
    const int unit = 16 * w + n;       // this lane's hidden unit
    const bool grp0w1 = (grp == 0) && (w == 1);   // head wave

    __shared__ __align__(16) float xrow[SQ + 8];
    __shared__ __align__(16) uint4 hbf[2][3][8];   // [buf][layer][64 fp16]
    __shared__ __align__(16) float ystage[32];     // head staging (1 wave)

    for (int i = tid; i < SQ; i += 768) xrow[i] = x[b * SQ + i];
    if (tid < 8) xrow[SQ + tid] = 0.f;
    if (tid < 48) ((uint4*)hbf)[tid] = make_uint4(0, 0, 0, 0);

    // ---- weights: MFMA B-fragments from workspace ----
    const int gbase = (grp == 0) ? 0 : (grp == 1) ? 8192 : 24576;
    const int KT    = (grp == 0) ? 2 : 4;
    const uint32_t* wbp = wpk + gbase;
    auto fr = [&](int j_, int kt_) {
        return *reinterpret_cast<const uint4*>(
            wbp + (((w * 4 + j_) * KT + kt_) * 64 + l) * 4);
    };
    uint4 w00 = fr(0, 0), w01 = fr(0, 1), w10 = fr(1, 0), w11 = fr(1, 1),
          w20 = fr(2, 0), w21 = fr(2, 1), w30 = fr(3, 0), w31 = fr(3, 1);
    pin4(w00); pin4(w01); pin4(w10); pin4(w11);
    pin4(w20); pin4(w21); pin4(w30); pin4(w31);
    uint4 w02 = {}, w03 = {}, w12 = {}, w13 = {},
          w22 = {}, w23 = {}, w32 = {}, w33 = {};
    if (grp != 0) {
        w02 = fr(0, 2); w03 = fr(0, 3); w12 = fr(1, 2); w13 = fr(1, 3);
        w22 = fr(2, 2); w23 = fr(2, 3); w32 = fr(3, 2); w33 = fr(3, 3);
        pin4(w02); pin4(w03); pin4(w12); pin4(w13);
        pin4(w22); pin4(w23); pin4(w32); pin4(w33);
    }
    // head fragments (grp0w1 only)
    uint4 wy2 = {}, wy3 = {};
    f32x4 cy = {0.f, 0.f, 0.f, 0.f};
    if (grp0w1) {
        wy2 = *reinterpret_cast<const uint4*>(wpk + 40960 + (0 * 64 + l) * 4);
        wy3 = *reinterpret_cast<const uint4*>(wpk + 40960 + (1 * 64 + l) * 4);
        pin4(wy2); pin4(wy3);
        const float bv = blin[0];
        cy = f32x4{bv, bv, bv, bv};
        pinv(cy);
    }

    // ---- persistent bias C-operands (gate j of unit -> row 64j + unit) ----
    const float* bi = (grp == 0) ? bih0 : (grp == 1) ? bih1 : bih2;
    const float* bh = (grp == 0) ? bhh0 : (grp == 1) ? bhh1 : bhh2;
    const float bs0 = bi[unit]       + bh[unit];
    const float bs1 = bi[64 + unit]  + bh[64 + unit];
    const float bs2 = bi[128 + unit] + bh[128 + unit];
    const float bs3 = bi[192 + unit] + bh[192 + unit];
    f32x4 cb0 = {bs0, bs0, bs0, bs0};  pinv(cb0);
    f32x4 cb1 = {bs1, bs1, bs1, bs1};  pinv(cb1);
    f32x4 cb2 = {bs2, bs2, bs2, bs2};  pinv(cb2);
    f32x4 cb3 = {bs3, bs3, bs3, bs3};  pinv(cb3);

    float wx0 = 0.f, wx1 = 0.f, wx2 = 0.f, wx3 = 0.f;
    if (grp == 0) {
        wx0 = Wih0[unit];       wx1 = Wih0[64 + unit];
        wx2 = Wih0[128 + unit]; wx3 = Wih0[192 + unit];
    }

    const int la = (grp == 2) ? 1 : 0;     // input-h source layer (A side)
    const int lb = grp;                    // own-h source layer (B side)
    const uint4* pA[2] = { &hbf[0][la][q], &hbf[1][la][q] };
    const uint4* pB[2] = { &hbf[0][lb][q], &hbf[1][lb][q] };
    const uint4* pY[2] = { &hbf[0][2][q],  &hbf[1][2][q] };   // head source
    _Float16* pH[2] = { (_Float16*)&hbf[0][grp][0] + unit,
                        (_Float16*)&hbf[1][grp][0] + unit };

    float cc = 0.f;                        // cell state (replicated all lanes)
    // carried input-side accumulators (grp1/2): acc_in(s) = Wih.h_in(s)+bias
    f32x4 ai0 = cb0, ai1 = cb1, ai2 = cb2, ai3 = cb3;

    __syncthreads();

    auto tick = [&](int T, int rd) {
        const int wr = rd ^ 1;
        float xT = 0.f;
        if (grp == 0) xT = xrow[T];        // padded; broadcast read

        f32x4 d0, d1, d2, d3;
        const uint4 a0 = pA[rd][0], a1 = pA[rd][4];
        if (grp == 0) {
            // single-sided: self matvec, step T
            d0 = mm(a0, w00, cb0);  d1 = mm(a0, w10, cb1);
            d2 = mm(a0, w20, cb2);  d3 = mm(a0, w30, cb3);
            d0 = mm(a1, w01, d0);   d1 = mm(a1, w11, d1);
            d2 = mm(a1, w21, d2);   d3 = mm(a1, w31, d3);
        } else {
            // finish step s = T-2*grp: self side (kt2,3) on carried acc_in
            const uint4 c0 = pB[rd][0], c1 = pB[rd][4];
            d0 = mm(c0, w02, ai0);  d1 = mm(c0, w12, ai1);
            d2 = mm(c0, w22, ai2);  d3 = mm(c0, w32, ai3);
            d0 = mm(c1, w03, d0);   d1 = mm(c1, w13, d1);
            d2 = mm(c1, w23, d2);   d3 = mm(c1, w33, d3);
            // prefetch input side (kt0,1) for step s+1; h_in(s+1) is age-1
            // published. Independent regs -> matrix pipe stays fed while
            // the activation below runs on the VALU.
            ai0 = mm(a0, w00, cb0); ai1 = mm(a0, w10, cb1);
            ai2 = mm(a0, w20, cb2); ai3 = mm(a0, w30, cb3);
            ai0 = mm(a1, w01, ai0); ai1 = mm(a1, w11, ai1);
            ai2 = mm(a1, w21, ai2); ai3 = mm(a1, w31, ai3);
        }

        if (grp0w1) {
            // head: y(T-5) = Wlin . h2(T-5) + blin; h2(T-5) published age-1.
            const int sy = T - 5;
            if (sy >= 0 && sy < SQ) {
                const uint4 y0 = pY[rd][0], y1 = pY[rd][4];
                f32x4 d4 = mm(y0, wy2, cy);
                d4 = mm(y1, wy3, d4);
                if (l == 0) ystage[sy & 31] = d4[0];   // ds_write, lgkm-only
                if ((sy & 31) == 31) {
                    const float yv = ystage[l & 31];
                    if (l < 32) out[b * SQ + (sy - 31) + l] = yv;
                }
            }
        }

        const int step = T - 2 * grp;
        if (step >= 0 && step < SQ) {      // wave-uniform guard
            // all 64 lanes redundantly process unit 16w+n (D rows replicated)
            float gi = d0[0], gf = d1[0], gg = d2[0], go = d3[0];
            if (grp == 0) {
                gi += wx0 * xT; gf += wx1 * xT;
                gg += wx2 * xT; go += wx3 * xT;
            }
            const float i_ = frcp(1.f + fexp2(gi * -1.44269504f));
            const float f_ = frcp(1.f + fexp2(gf * -1.44269504f));
            const float o_ = frcp(1.f + fexp2(go * -1.44269504f));
            const float tg = 2.f * frcp(1.f + fexp2(gg * -2.88539008f)) - 1.f;
            cc = f_ * cc + i_ * tg;
            const float tc = fminf(fmaxf(cc, -15.f), 15.f);
            const float e  = fexp2(tc * -2.88539008f);
            const float h  = o_ * ((1.f - e) * frcp(1.f + e));
            if (l < 16) {
                pH[wr][0] = (_Float16)h;
                if (step == SQ - 1) {
                    out[NB * SQ + grp * NB * HH + b * HH + unit] = h;
                    out[NB * SQ + 3 * NB * HH + grp * NB * HH + b * HH + unit] = cc;
                }
            }
        }
        __syncthreads();
    };

    // ticks 0..SQ+5 (l0 step=T, l1=T-2, l2=T-4, head y=T-5 -> needs T=SQ+4)
    for (int T = 0; T < SQ + 6; T += 2) {
        tick(T, 0);
        tick(T + 1, 1);
    }
}

extern "C" void kernel_launch(void* const* d_in, const int* in_sizes, int n_in,
                              void* d_out, int out_size, void* d_ws, size_t ws_size,
                              hipStream_t stream) {
    const float* x    = (const float*)d_in[0];
    const float* Wih0 = (const float*)d_in[1];
    const float* Whh0 = (const float*)d_in[2];
    const float* bih0 = (const float*)d_in[3];
    const float* bhh0 = (const float*)d_in[4];
    const float* Wih1 = (const float*)d_in[5];
    const float* Whh1 = (const float*)d_in[6];
    const float* bih1 = (const float*)d_in[7];
    const float* bhh1 = (const float*)d_in[8];
    const float* Wih2 = (const float*)d_in[9];
    const float* Whh2 = (const float*)d_in[10];
    const float* bih2 = (const float*)d_in[11];
    const float* bhh2 = (const float*)d_in[12];
    const float* Wlin = (const float*)d_in[13];
    const float* blin = (const float*)d_in[14];
    float* out = (float*)d_out;

    uint32_t* wpk = (uint32_t*)d_ws;   // 41472 u32 = 162 KiB < ws_size
    prep_weights<<<162, 256, 0, stream>>>(Whh0, Wih1, Whh1, Wih2, Whh2, Wlin, wpk);
    lstm3_fused<<<NB, 768, 0, stream>>>(x, Wih0, bih0, bhh0,
                                        bih1, bhh1, bih2, bhh2,
                                        blin, wpk, out);
}